// Round 9
// baseline (35.149 us; speedup 1.0000x reference)
//
#include <hip/hip_runtime.h>

// ROUND 8 = DECOMPOSITION PROBE. Kernel is byte-identical to round 7 (best,
// 20.25us). kernel_launch launches it TWICE back-to-back: the kernel is
// idempotent (out = pure function of inputs), so output is unchanged and
// deterministic. dur_us(round8) - dur_us(round7) = true kernel time K,
// separating K from fixed graph/launch overhead, which rocprof can't show us
// (the 39us ws-poison fills occupy the top-5 table).
//   K <= 4us -> overhead-dominated -> roofline next round.
//   K >= 6us -> symmetric (half-exp) rewrite is worth it.

#define NN   8192
#define TPB  512
#define RB   16              // rows per block (all threads share these rows)
#define NH   (RB / 2)        // 8 v2f row-groups
#define JPT  (NN / TPB)      // 16 j per thread
#define NWV  (TPB / 64)      // 8 waves per block

typedef float v2f __attribute__((ext_vector_type(2)));

#if __has_builtin(__builtin_amdgcn_exp2f)
#define EXP2(x) __builtin_amdgcn_exp2f(x)
#else
#define EXP2(x) exp2f(x)
#endif

__global__ __launch_bounds__(TPB, 4) void fused_kernel(
    const float2* __restrict__ XX, const float* __restrict__ W1,
    const float* __restrict__ b1, const float* __restrict__ W2,
    const float* __restrict__ b2, float* __restrict__ out)
{
    __shared__ float ls[NWV], lq[NWV];
    __shared__ float csh;
    __shared__ float wred[NWV][RB];

    int tid = threadIdx.x;
    float w00 = W1[0], w01 = W1[1], w10 = W1[2], w11 = W1[3];
    float b0 = b1[0], bb1 = b1[1];

    // --- stats partial (identical order in every block -> identical c) ---
    const float4* XX4 = (const float4*)XX;
    float s = 0.f, q = 0.f;
#pragma unroll
    for (int ii = 0; ii < (NN / 2) / TPB; ii++) {      // 8 unrolled iters
        float4 v = XX4[ii * TPB + tid];
        float y0 = fmaf(v.y, w01, fmaf(v.x, w00, b0));
        float y1 = fmaf(v.y, w11, fmaf(v.x, w10, bb1));
        float y2 = fmaf(v.w, w01, fmaf(v.z, w00, b0));
        float y3 = fmaf(v.w, w11, fmaf(v.z, w10, bb1));
        s += (y0 + y1) + (y2 + y3);
        q += fmaf(y0, y0, y1 * y1) + fmaf(y2, y2, y3 * y3);
    }
#pragma unroll
    for (int o = 32; o > 0; o >>= 1) {
        s += __shfl_xor(s, o, 64);
        q += __shfl_xor(q, o, 64);
    }
    int wv = tid >> 6;
    if ((tid & 63) == 0) { ls[wv] = s; lq[wv] = q; }
    __syncthreads();
    if (tid == 0) {
        float S = 0.f, Q = 0.f;
#pragma unroll
        for (int i = 0; i < NWV; i++) { S += ls[i]; Q += lq[i]; }
        float M = (float)(2 * NN);
        float var = (Q - S * S / M) / (M - 1.0f);   // ddof=1
        csh = 1.4426950408889634f / var;            // c = log2e / var
    }
    __syncthreads();
    float c = csh;

    // --- row registers: RB=16 rows per block, 8 v2f groups per thread ---
    int rowBase = blockIdx.x * RB;
    v2f A0p[NH], A1p[NH], Bp[NH], accp[NH];
    const v2f cp = {c, c};
    float m2c = -2.0f * c;
#pragma unroll
    for (int h = 0; h < NH; h++) {
        float2 xa = XX[rowBase + 2 * h];
        float2 xb = XX[rowBase + 2 * h + 1];
        float ya0 = fmaf(xa.y, w01, fmaf(xa.x, w00, b0));
        float ya1 = fmaf(xa.y, w11, fmaf(xa.x, w10, bb1));
        float yb0 = fmaf(xb.y, w01, fmaf(xb.x, w00, b0));
        float yb1 = fmaf(xb.y, w11, fmaf(xb.x, w10, bb1));
        A0p[h] = (v2f){m2c * ya0, m2c * yb0};
        A1p[h] = (v2f){m2c * ya1, m2c * yb1};
        Bp[h]  = (v2f){c * fmaf(ya0, ya0, ya1 * ya1), c * fmaf(yb0, yb0, yb1 * yb1)};
        accp[h] = (v2f){0.f, 0.f};
    }

    // --- main loop: j straight from global (L2-resident), no LDS, no barriers ---
#pragma unroll 4
    for (int k = 0; k < JPT; k++) {
        int j = k * TPB + tid;                 // lanes -> consecutive j: coalesced
        float2 xj = XX[j];
        float wj = W2[j];
        float y0 = fmaf(xj.y, w01, fmaf(xj.x, w00, b0));
        float y1 = fmaf(xj.y, w11, fmaf(xj.x, w10, bb1));
        float rj = fmaf(y0, y0, y1 * y1);
        float gw = -0.34657359027997264f * wj; // -(ln2)/2 * W2_j
        v2f qx = {y0, y0};
        v2f qy = {y1, y1};
        v2f qz = {rj, rj};
        v2f qw = {gw, gw};
#pragma unroll
        for (int h = 0; h < NH; h++) {
            v2f kc = __builtin_elementwise_fma(A0p[h], qx,
                     __builtin_elementwise_fma(A1p[h], qy,
                     __builtin_elementwise_fma(cp, qz, Bp[h])));
            v2f e;
            e.x = EXP2(kc.x);                  // v_exp_f32
            e.y = EXP2(kc.y);
            accp[h] = __builtin_elementwise_fma(qw * kc, e, accp[h]);
        }
    }

    // --- reduce: 512 threads all hold partials for the same 16 rows ---
#pragma unroll
    for (int h = 0; h < NH; h++) {
#pragma unroll
        for (int o = 1; o <= 32; o <<= 1) {
            accp[h].x += __shfl_xor(accp[h].x, o, 64);
            accp[h].y += __shfl_xor(accp[h].y, o, 64);
        }
    }
    if ((tid & 63) == 0) {
#pragma unroll
        for (int h = 0; h < NH; h++) {
            wred[wv][2 * h]     = accp[h].x;
            wred[wv][2 * h + 1] = accp[h].y;
        }
    }
    __syncthreads();
    if (tid < RB) {
        float sR = b2[0];
#pragma unroll
        for (int ww = 0; ww < NWV; ww++) sR += wred[ww][tid];
        out[rowBase + tid] = sR;
    }
}

extern "C" void kernel_launch(void* const* d_in, const int* in_sizes, int n_in,
                              void* d_out, int out_size, void* d_ws, size_t ws_size,
                              hipStream_t stream)
{
    const float* XX = (const float*)d_in[0];
    const float* W1 = (const float*)d_in[1];
    const float* b1 = (const float*)d_in[2];
    const float* W2 = (const float*)d_in[3];
    const float* b2 = (const float*)d_in[4];
    float* out = (float*)d_out;

    // PROBE: two identical launches. Second recomputes the same output
    // (pure function of inputs) -> correctness and determinism preserved.
    fused_kernel<<<NN / RB, TPB, 0, stream>>>((const float2*)XX, W1, b1, W2, b2, out);
    fused_kernel<<<NN / RB, TPB, 0, stream>>>((const float2*)XX, W1, b1, W2, b2, out);
}

// Round 12
// 21.591 us; speedup vs baseline: 1.6280x; 1.6280x over previous
//
#include <hip/hip_runtime.h>

// Round 11 = round 7 (known-good, 20.25us, absmax 32) with RB 16->32.
// BIT-EXACT argument: each row's accumulation stream depends only on the
// thread j-subset (j = k*TPB+tid, unchanged), lane/wave reduce order
// (unchanged), and per-pair arithmetic (unchanged). RB only changes WHICH
// block computes a row -> outputs must be bit-identical to r7 (absmax 32).
// Gains: per-CU stats passes 2->1 (grid 256 = 1 block/CU), per-j prep
// amortized over 32 rows, half the dispatches. launch_bounds (512,2) raises
// VGPR cap to 256 for the 128-VGPR row state (16 v2f quadruples).
// r9/r10's register-array preload structure is abandoned (2x mystery fails).

#define NN   8192
#define TPB  512
#define RB   32              // rows per block (all threads share these rows)
#define NH   (RB / 2)        // 16 v2f row-groups
#define JPT  (NN / TPB)      // 16 j per thread
#define NWV  (TPB / 64)      // 8 waves per block

typedef float v2f __attribute__((ext_vector_type(2)));

#if __has_builtin(__builtin_amdgcn_exp2f)
#define EXP2(x) __builtin_amdgcn_exp2f(x)
#else
#define EXP2(x) exp2f(x)
#endif

__global__ __launch_bounds__(TPB, 2) void fused_kernel(
    const float2* __restrict__ XX, const float* __restrict__ W1,
    const float* __restrict__ b1, const float* __restrict__ W2,
    const float* __restrict__ b2, float* __restrict__ out)
{
    __shared__ float ls[NWV], lq[NWV];
    __shared__ float csh;
    __shared__ float wred[NWV][RB];

    int tid = threadIdx.x;
    float w00 = W1[0], w01 = W1[1], w10 = W1[2], w11 = W1[3];
    float b0 = b1[0], bb1 = b1[1];

    // --- stats partial (identical order in every block -> identical c) ---
    const float4* XX4 = (const float4*)XX;
    float s = 0.f, q = 0.f;
#pragma unroll
    for (int ii = 0; ii < (NN / 2) / TPB; ii++) {      // 8 unrolled iters
        float4 v = XX4[ii * TPB + tid];
        float y0 = fmaf(v.y, w01, fmaf(v.x, w00, b0));
        float y1 = fmaf(v.y, w11, fmaf(v.x, w10, bb1));
        float y2 = fmaf(v.w, w01, fmaf(v.z, w00, b0));
        float y3 = fmaf(v.w, w11, fmaf(v.z, w10, bb1));
        s += (y0 + y1) + (y2 + y3);
        q += fmaf(y0, y0, y1 * y1) + fmaf(y2, y2, y3 * y3);
    }
#pragma unroll
    for (int o = 32; o > 0; o >>= 1) {
        s += __shfl_xor(s, o, 64);
        q += __shfl_xor(q, o, 64);
    }
    int wv = tid >> 6;
    if ((tid & 63) == 0) { ls[wv] = s; lq[wv] = q; }
    __syncthreads();
    if (tid == 0) {
        float S = 0.f, Q = 0.f;
#pragma unroll
        for (int i = 0; i < NWV; i++) { S += ls[i]; Q += lq[i]; }
        float M = (float)(2 * NN);
        float var = (Q - S * S / M) / (M - 1.0f);   // ddof=1
        csh = 1.4426950408889634f / var;            // c = log2e / var
    }
    __syncthreads();
    float c = csh;

    // --- row registers: RB=32 rows per block, 16 v2f groups per thread ---
    int rowBase = blockIdx.x * RB;
    v2f A0p[NH], A1p[NH], Bp[NH], accp[NH];
    const v2f cp = {c, c};
    float m2c = -2.0f * c;
#pragma unroll
    for (int h = 0; h < NH; h++) {
        float2 xa = XX[rowBase + 2 * h];
        float2 xb = XX[rowBase + 2 * h + 1];
        float ya0 = fmaf(xa.y, w01, fmaf(xa.x, w00, b0));
        float ya1 = fmaf(xa.y, w11, fmaf(xa.x, w10, bb1));
        float yb0 = fmaf(xb.y, w01, fmaf(xb.x, w00, b0));
        float yb1 = fmaf(xb.y, w11, fmaf(xb.x, w10, bb1));
        A0p[h] = (v2f){m2c * ya0, m2c * yb0};
        A1p[h] = (v2f){m2c * ya1, m2c * yb1};
        Bp[h]  = (v2f){c * fmaf(ya0, ya0, ya1 * ya1), c * fmaf(yb0, yb0, yb1 * yb1)};
        accp[h] = (v2f){0.f, 0.f};
    }

    // --- main loop: j straight from global (L2-resident), no LDS, no barriers ---
#pragma unroll 4
    for (int k = 0; k < JPT; k++) {
        int j = k * TPB + tid;                 // lanes -> consecutive j: coalesced
        float2 xj = XX[j];
        float wj = W2[j];
        float y0 = fmaf(xj.y, w01, fmaf(xj.x, w00, b0));
        float y1 = fmaf(xj.y, w11, fmaf(xj.x, w10, bb1));
        float rj = fmaf(y0, y0, y1 * y1);
        float gw = -0.34657359027997264f * wj; // -(ln2)/2 * W2_j
        v2f qx = {y0, y0};
        v2f qy = {y1, y1};
        v2f qz = {rj, rj};
        v2f qw = {gw, gw};
#pragma unroll
        for (int h = 0; h < NH; h++) {
            v2f kc = __builtin_elementwise_fma(A0p[h], qx,
                     __builtin_elementwise_fma(A1p[h], qy,
                     __builtin_elementwise_fma(cp, qz, Bp[h])));
            v2f e;
            e.x = EXP2(kc.x);                  // v_exp_f32
            e.y = EXP2(kc.y);
            accp[h] = __builtin_elementwise_fma(qw * kc, e, accp[h]);
        }
    }

    // --- reduce: 512 threads all hold partials for the same 32 rows ---
#pragma unroll
    for (int h = 0; h < NH; h++) {
#pragma unroll
        for (int o = 1; o <= 32; o <<= 1) {
            accp[h].x += __shfl_xor(accp[h].x, o, 64);
            accp[h].y += __shfl_xor(accp[h].y, o, 64);
        }
    }
    if ((tid & 63) == 0) {
#pragma unroll
        for (int h = 0; h < NH; h++) {
            wred[wv][2 * h]     = accp[h].x;
            wred[wv][2 * h + 1] = accp[h].y;
        }
    }
    __syncthreads();
    if (tid < RB) {
        float sR = b2[0];
#pragma unroll
        for (int ww = 0; ww < NWV; ww++) sR += wred[ww][tid];
        out[rowBase + tid] = sR;
    }
}

extern "C" void kernel_launch(void* const* d_in, const int* in_sizes, int n_in,
                              void* d_out, int out_size, void* d_ws, size_t ws_size,
                              hipStream_t stream)
{
    const float* XX = (const float*)d_in[0];
    const float* W1 = (const float*)d_in[1];
    const float* b1 = (const float*)d_in[2];
    const float* W2 = (const float*)d_in[3];
    const float* b2 = (const float*)d_in[4];
    float* out = (float*)d_out;

    fused_kernel<<<NN / RB, TPB, 0, stream>>>((const float2*)XX, W1, b1, W2, b2, out);
}